// Round 8
// baseline (324.071 us; speedup 1.0000x reference)
//
#include <hip/hip_runtime.h>
#include <hip/hip_bf16.h>

typedef __bf16 bf16_t;
typedef __bf16 bf16x8 __attribute__((ext_vector_type(8)));
typedef __bf16 bf16x4 __attribute__((ext_vector_type(4)));
typedef float f32x4 __attribute__((ext_vector_type(4)));
typedef float f32x16 __attribute__((ext_vector_type(16)));

// 1/sqrt(128) * log2(e)  (folded into Q so that P = exp2(S))
#define SCALE_Q2 0.12752518895325724f

__device__ __forceinline__ void gload_lds16(const void* g, void* l) {
  __builtin_amdgcn_global_load_lds(
      (const __attribute__((address_space(1))) void*)g,
      (__attribute__((address_space(3))) void*)l, 16, 0, 0);
}

// ---------------- fp32 -> bf16 convert ----------------
__global__ __launch_bounds__(256) void cvt_f32_bf16(
    const float* __restrict__ src, bf16_t* __restrict__ dst, int n4) {
  int i = blockIdx.x * 256 + threadIdx.x;
  const int stride = gridDim.x * 256;
  for (; i < n4; i += stride) {
    f32x4 v = *reinterpret_cast<const f32x4*>(src + (size_t)i * 4);
    bf16x4 r;
    r[0] = (bf16_t)v[0]; r[1] = (bf16_t)v[1];
    r[2] = (bf16_t)v[2]; r[3] = (bf16_t)v[3];
    *reinterpret_cast<bf16x4*>(dst + (size_t)i * 4) = r;
  }
}

// fused wq|wk|wv -> wqkv convert (dst contiguous, 3 sources)
__global__ __launch_bounds__(256) void cvt_qkvw(
    const float* __restrict__ wq, const float* __restrict__ wk,
    const float* __restrict__ wv, bf16_t* __restrict__ dst) {
  const int i = blockIdx.x * 256 + threadIdx.x;
  const int e = i * 4;
  const float* src;
  if (e < 4194304) src = wq + e;
  else if (e < 5242880) src = wk + (e - 4194304);
  else src = wv + (e - 5242880);
  f32x4 v = *reinterpret_cast<const f32x4*>(src);
  bf16x4 r;
  r[0] = (bf16_t)v[0]; r[1] = (bf16_t)v[1];
  r[2] = (bf16_t)v[2]; r[3] = (bf16_t)v[3];
  *reinterpret_cast<bf16x4*>(dst + e) = r;
}

// ---------------- 256x256 counted-vmcnt GEMM: C = A[M][K] * W[N][K]^T -----
// BK=32, 8 waves (2Mx4N), per-wave 128x64, tri-buffered LDS (96KB) so the
// boundary wait is vmcnt(4) (next tile in flight), raw s_barrier (no drain).
// LDS swizzle: 16B-chunk c ^= (row>>1)&3 (frag reads spread across all 8
// bank-quads, 2 lanes each = free). Source pre-swizzled (involution).
template <typename OutT>
__global__ __launch_bounds__(512, 2) void gemm256(
    const bf16_t* __restrict__ A, const bf16_t* __restrict__ W,
    OutT* __restrict__ C, int M, int N, int K, int nbx) {
  __shared__ __align__(16) bf16_t Ab[3][256 * 32];
  __shared__ __align__(16) bf16_t Wb[3][256 * 32];
  const int tid = threadIdx.x;
  const int lane = tid & 63;
  const int wid = tid >> 6;
  const int wr = wid >> 2, wc = wid & 3;
  const int l15 = lane & 15, lg = lane >> 4;

  // XCD-aware bijective swizzle (gridDim.x % 8 == 0 for our shapes)
  const int nwg = gridDim.x;
  const int cpx = nwg >> 3;
  const int swz = (blockIdx.x & 7) * cpx + (blockIdx.x >> 3);
  const int bx = swz % nbx, by = swz / nbx;
  const long r0 = (long)by * 256;
  const long c0 = (long)bx * 256;

  const int nt = K >> 5;

  // staging: thread tid stages 16B chunk idx=tid of each 128-row half.
  const int srow = tid >> 2;                       // row within half
  const int ssc = (tid & 3) ^ ((tid >> 3) & 3);    // pre-swizzled source chunk
  const long aoff = ssc * 8;

  auto STAGE_A = [&](int buf, int kt) {
    const long k0 = (long)kt * 32;
#pragma unroll
    for (int h = 0; h < 2; ++h)
      gload_lds16(A + (r0 + h * 128 + srow) * K + k0 + aoff,
                  &Ab[buf][(h * 512 + tid) * 8]);
  };
  auto STAGE_W = [&](int buf, int kt) {
    const long k0 = (long)kt * 32;
#pragma unroll
    for (int h = 0; h < 2; ++h)
      gload_lds16(W + (c0 + h * 128 + srow) * K + k0 + aoff,
                  &Wb[buf][(h * 512 + tid) * 8]);
  };

  f32x4 acc[8][4];
#pragma unroll
  for (int mi = 0; mi < 8; ++mi)
#pragma unroll
    for (int ni = 0; ni < 4; ++ni)
#pragma unroll
      for (int j = 0; j < 4; ++j) acc[mi][ni][j] = 0.f;

  // prologue: stage tiles 0 and 1
  STAGE_A(0, 0); STAGE_W(0, 0);
  STAGE_A(1, 1); STAGE_W(1, 1);
  asm volatile("s_waitcnt vmcnt(4)" ::: "memory");  // tile 0 landed
  __builtin_amdgcn_s_barrier();

  int cur = 0;
  for (int t = 0; t < nt; ++t) {
    const int nxt = (cur + 2 >= 3) ? (cur - 1) : (cur + 2);
    const char* ab = (const char*)&Ab[cur][0];
    const char* wb = (const char*)&Wb[cur][0];

    // ---- phase 0: stage A(t+2); read W-frags + A-frags mf0-3; MFMA ----
    if (t + 2 < nt) STAGE_A(nxt, t + 2);
    bf16x8 wf[4];
#pragma unroll
    for (int nf = 0; nf < 4; ++nf) {
      const int r = wc * 64 + nf * 16 + l15;
      wf[nf] = *reinterpret_cast<const bf16x8*>(
          wb + r * 64 + ((lg ^ ((r >> 1) & 3)) << 4));
    }
    bf16x8 af[4];
#pragma unroll
    for (int mf = 0; mf < 4; ++mf) {
      const int r = wr * 128 + mf * 16 + l15;
      af[mf] = *reinterpret_cast<const bf16x8*>(
          ab + r * 64 + ((lg ^ ((r >> 1) & 3)) << 4));
    }
    __builtin_amdgcn_s_barrier();
    __builtin_amdgcn_s_setprio(1);
#pragma unroll
    for (int mf = 0; mf < 4; ++mf)
#pragma unroll
      for (int nf = 0; nf < 4; ++nf)
        acc[mf][nf] = __builtin_amdgcn_mfma_f32_16x16x32_bf16(
            af[mf], wf[nf], acc[mf][nf], 0, 0, 0);
    __builtin_amdgcn_s_setprio(0);
    __builtin_amdgcn_s_barrier();

    // ---- phase 1: stage W(t+2); read A-frags mf4-7; MFMA ----
    if (t + 2 < nt) STAGE_W(nxt, t + 2);
#pragma unroll
    for (int mf = 0; mf < 4; ++mf) {
      const int r = wr * 128 + 64 + mf * 16 + l15;
      af[mf] = *reinterpret_cast<const bf16x8*>(
          ab + r * 64 + ((lg ^ ((r >> 1) & 3)) << 4));
    }
    __builtin_amdgcn_s_barrier();
    __builtin_amdgcn_s_setprio(1);
#pragma unroll
    for (int mf = 0; mf < 4; ++mf)
#pragma unroll
      for (int nf = 0; nf < 4; ++nf)
        acc[mf + 4][nf] = __builtin_amdgcn_mfma_f32_16x16x32_bf16(
            af[mf], wf[nf], acc[mf + 4][nf], 0, 0, 0);
    __builtin_amdgcn_s_setprio(0);
    // boundary: tile t+1 must be fully landed; t+2 stays in flight
    asm volatile("s_waitcnt vmcnt(4)" ::: "memory");
    __builtin_amdgcn_s_barrier();
    cur = (cur + 1 >= 3) ? 0 : (cur + 1);
  }

  // ---- epilogue ----
#pragma unroll
  for (int mi = 0; mi < 8; ++mi)
#pragma unroll
    for (int ni = 0; ni < 4; ++ni)
#pragma unroll
      for (int j = 0; j < 4; ++j) {
        const long row = r0 + wr * 128 + mi * 16 + lg * 4 + j;
        const long col = c0 + wc * 64 + ni * 16 + l15;
        const float v = acc[mi][ni][j];
        if constexpr (__is_same(OutT, float))
          C[row * N + col] = v;
        else
          C[row * N + col] = (bf16_t)v;
      }
}

// ---------------- RoPE: qkv[4096][3072] -> Qr, Kr (coalesced only) --------
__global__ __launch_bounds__(256) void rope_layout(
    const bf16_t* __restrict__ qkv, const float* __restrict__ fc,
    const float* __restrict__ fs, bf16_t* __restrict__ Qr,
    bf16_t* __restrict__ Kr) {
  const int n = blockIdx.x;
  const int b = n >> 11, t = n & 2047;
  const int tid = threadIdx.x;
  const bf16_t* row = qkv + (size_t)n * 3072;

#pragma unroll
  for (int i = 0; i < 4; ++i) {
    const int p = i * 256 + tid;
    const int h = p >> 6, j = p & 63;
    const float t0 = (float)row[h * 128 + 2 * j];
    const float t1 = (float)row[h * 128 + 2 * j + 1];
    const float c = fc[t * 64 + j], s = fs[t * 64 + j];
    const size_t dst = ((size_t)(b * 16 + h) * 2048 + t) * 128 + 2 * j;
    Qr[dst] = (bf16_t)((t0 * c - t1 * s) * SCALE_Q2);
    Qr[dst + 1] = (bf16_t)((t0 * s + t1 * c) * SCALE_Q2);
  }
  {
    const int kvh = tid >> 6, j = tid & 63;
    const float t0 = (float)row[2048 + kvh * 128 + 2 * j];
    const float t1 = (float)row[2048 + kvh * 128 + 2 * j + 1];
    const float c = fc[t * 64 + j], s = fs[t * 64 + j];
    const size_t dst = ((size_t)(b * 4 + kvh) * 2048 + t) * 128 + 2 * j;
    Kr[dst] = (bf16_t)(t0 * c - t1 * s);
    Kr[dst + 1] = (bf16_t)(t0 * s + t1 * c);
  }
}

// ---------------- V transpose: qkv -> Vt[B*4][128][2048], LDS-tiled --------
// Token columns permuted within 16-groups (swap bits 2<->3 of t&15).
__global__ __launch_bounds__(256) void v_trans(
    const bf16_t* __restrict__ qkv, bf16_t* __restrict__ Vt) {
  __shared__ bf16_t L[64][68];
  const int bid = blockIdx.x;
  const int tt = bid & 31;
  const int dt2 = (bid >> 5) & 1;
  const int bk = bid >> 6;
  const int b = bk >> 2, kvh = bk & 3;
  const int t0 = tt * 64, d0 = dt2 * 64;
  const int r = threadIdx.x >> 4;
  const int c4 = (threadIdx.x & 15) * 4;

#pragma unroll
  for (int it = 0; it < 4; ++it) {
    const int tl = r + it * 16;
    const int tp = (tl & ~15) |
                   ((tl & 3) | ((tl & 4) << 1) | ((tl & 8) >> 1));
    const bf16_t* src = qkv + (size_t)(b * 2048 + t0 + tl) * 3072 + 2560 +
                        kvh * 128 + d0 + c4;
    *reinterpret_cast<bf16x4*>(&L[tp][c4]) =
        *reinterpret_cast<const bf16x4*>(src);
  }
  __syncthreads();
#pragma unroll
  for (int it = 0; it < 4; ++it) {
    const int dr = r + it * 16;
    bf16x4 v;
#pragma unroll
    for (int j = 0; j < 4; ++j) v[j] = L[c4 + j][dr];
    *reinterpret_cast<bf16x4*>(Vt + ((size_t)bk * 128 + d0 + dr) * 2048 +
                               t0 + c4) = v;
  }
}

// ---------------- causal GQA flash attention (32x32 MFMA, swapped QK) ------
__global__ __launch_bounds__(256, 2) void attn_fwd(
    const bf16_t* __restrict__ Qr, const bf16_t* __restrict__ Kr,
    const bf16_t* __restrict__ Vt, bf16_t* __restrict__ Oout) {
  __shared__ __align__(16) bf16_t Klds[2][128 * 128];
  const int tid = threadIdx.x;
  const int lane = tid & 63, w = tid >> 6;
  const int l31 = lane & 31, hi = lane >> 5;
  const int sidx = blockIdx.x >> 5;
  const int hb = blockIdx.x & 31;
  const int h = hb & 15, b = hb >> 4;
  const int kvh = h >> 2;
  const int st = (sidx < 8) ? (15 - sidx) : (sidx - 8);

  const bf16_t* Kbase = Kr + ((size_t)(b * 4 + kvh) * 2048) * 128;
  const bf16_t* Vbase = Vt + ((size_t)(b * 4 + kvh) * 128) * 2048;

  const int qbw = st * 128 + w * 32;
  const bf16_t* Qbase = Qr + ((size_t)(b * 16 + h) * 2048 + qbw + l31) * 128;

  auto STAGE = [&](bf16_t* dst, int kt) {
    const int k0 = kt * 128;
#pragma unroll
    for (int i = 0; i < 8; ++i) {
      const int c = i * 256 + tid;
      const int row = c >> 4;
      const int col = c & 15;
      const int scol = col ^ (row & 15);
      gload_lds16(Kbase + (size_t)(k0 + row) * 128 + scol * 8, dst + c * 8);
    }
  };

  STAGE(&Klds[0][0], 0);

  bf16x8 qf[8];
#pragma unroll
  for (int dt = 0; dt < 8; ++dt)
    qf[dt] = *reinterpret_cast<const bf16x8*>(Qbase + dt * 16 + hi * 8);

  f32x16 o[4];
#pragma unroll
  for (int d = 0; d < 4; ++d)
#pragma unroll
    for (int r = 0; r < 16; ++r) o[d][r] = 0.f;
  float lsum = 0.f;

  const int nt = st + 1;
  int cur = 0;
  for (int kt = 0; kt < nt; ++kt) {
    const int k0 = kt * 128;
    const bool last = (kt == nt - 1);
    const int kfmax = last ? w : 3;

    __syncthreads();
    if (kt + 1 < nt) STAGE(&Klds[cur ^ 1][0], kt + 1);

    const char* KB = (const char*)&Klds[cur][0];

    f32x16 s[4];
    __builtin_amdgcn_s_setprio(1);
#pragma unroll
    for (int kf = 0; kf < 4; ++kf) {
      if (kf <= kfmax) {
#pragma unroll
        for (int r = 0; r < 16; ++r) s[kf][r] = 0.f;
#pragma unroll
        for (int dt = 0; dt < 8; ++dt) {
          const int boff = (kf * 32 + l31) * 256 +
                           ((dt * 32 + hi * 16) ^ ((l31 & 15) << 4));
          bf16x8 ka = *reinterpret_cast<const bf16x8*>(KB + boff);
          s[kf] = __builtin_amdgcn_mfma_f32_32x32x16_bf16(ka, qf[dt], s[kf],
                                                          0, 0, 0);
        }
      }
    }
    __builtin_amdgcn_s_setprio(0);

#pragma unroll
    for (int kf = 0; kf < 4; ++kf) {
      if (kf <= kfmax) {
        const bool diag = last && (kf == w);
        float p[16];
#pragma unroll
        for (int r = 0; r < 16; ++r) {
          float e = exp2f(s[kf][r]);
          if (diag) {
            const int crow = (r & 3) + 8 * (r >> 2) + 4 * hi;
            if (crow > l31) e = 0.f;
          }
          p[r] = e;
        }
        const float t0 = (p[0] + p[1]) + (p[2] + p[3]);
        const float t1 = (p[4] + p[5]) + (p[6] + p[7]);
        const float t2 = (p[8] + p[9]) + (p[10] + p[11]);
        const float t3 = (p[12] + p[13]) + (p[14] + p[15]);
        lsum += (t0 + t1) + (t2 + t3);
#pragma unroll
        for (int kc = 0; kc < 2; ++kc) {
          unsigned int u0, u1, u2, u3;
          asm("v_cvt_pk_bf16_f32 %0, %1, %2" : "=v"(u0)
              : "v"(p[8 * kc + 0]), "v"(p[8 * kc + 1]));
          asm("v_cvt_pk_bf16_f32 %0, %1, %2" : "=v"(u1)
              : "v"(p[8 * kc + 2]), "v"(p[8 * kc + 3]));
          asm("v_cvt_pk_bf16_f32 %0, %1, %2" : "=v"(u2)
              : "v"(p[8 * kc + 4]), "v"(p[8 * kc + 5]));
          asm("v_cvt_pk_bf16_f32 %0, %1, %2" : "=v"(u3)
              : "v"(p[8 * kc + 6]), "v"(p[8 * kc + 7]));
          union { unsigned int u[4]; bf16x8 v; } pb;
          pb.u[0] = u0; pb.u[1] = u1; pb.u[2] = u2; pb.u[3] = u3;
          __builtin_amdgcn_s_setprio(1);
#pragma unroll
          for (int dtile = 0; dtile < 4; ++dtile) {
            bf16x8 va = *reinterpret_cast<const bf16x8*>(
                Vbase + (size_t)(dtile * 32 + l31) * 2048 + k0 + kf * 32 +
                kc * 16 + hi * 8);
            o[dtile] = __builtin_amdgcn_mfma_f32_32x32x16_bf16(va, pb.v,
                                                               o[dtile],
                                                               0, 0, 0);
          }
          __builtin_amdgcn_s_setprio(0);
        }
      }
    }
    cur ^= 1;
  }

  const float ltot = lsum + __shfl_xor(lsum, 32);
  const float inv = 1.f / ltot;
  bf16_t* Obase = Oout + ((size_t)b * 2048 + qbw + l31) * 2048 + h * 128;
#pragma unroll
  for (int dtile = 0; dtile < 4; ++dtile)
#pragma unroll
    for (int g = 0; g < 4; ++g) {
      bf16x4 stv;
#pragma unroll
      for (int j = 0; j < 4; ++j)
        stv[j] = (bf16_t)(o[dtile][g * 4 + j] * inv);
      *reinterpret_cast<bf16x4*>(Obase + dtile * 32 + 8 * g + 4 * hi) = stv;
    }
}

// ---------------- host launch ----------------
extern "C" void kernel_launch(void* const* d_in, const int* in_sizes, int n_in,
                              void* d_out, int out_size, void* d_ws,
                              size_t ws_size, hipStream_t stream) {
  const float* x  = (const float*)d_in[0];
  const float* wq = (const float*)d_in[1];
  const float* wk = (const float*)d_in[2];
  const float* wv = (const float*)d_in[3];
  const float* wo = (const float*)d_in[4];
  const float* fc = (const float*)d_in[5];
  const float* fs = (const float*)d_in[6];
  float* out = (float*)d_out;

  char* ws = (char*)d_ws;
  bf16_t* xb      = (bf16_t*)(ws + 0);
  bf16_t* wqkv    = (bf16_t*)(ws + 16777216);
  bf16_t* wo_b    = (bf16_t*)(ws + 29360128);
  bf16_t* qkv     = (bf16_t*)(ws + 37748736);
  bf16_t* Qr      = (bf16_t*)(ws + 62914560);
  bf16_t* Kr      = (bf16_t*)(ws + 79691776);
  bf16_t* Vt      = (bf16_t*)(ws + 83886080);
  bf16_t* attn_o  = xb;

  const int M = 4096;

  cvt_f32_bf16<<<2048, 256, 0, stream>>>(x, xb, 2097152);
  cvt_qkvw<<<6144, 256, 0, stream>>>(wq, wk, wv, wqkv);
  cvt_f32_bf16<<<1024, 256, 0, stream>>>(wo, wo_b, 1048576);

  // QKV projection: 4096x3072x2048, 256^2 tiles -> 12x16 = 192 blocks
  gemm256<bf16_t><<<192, 512, 0, stream>>>(xb, wqkv, qkv, M, 3072, 2048, 12);

  rope_layout<<<4096, 256, 0, stream>>>(qkv, fc, fs, Qr, Kr);
  v_trans<<<512, 256, 0, stream>>>(qkv, Vt);

  attn_fwd<<<512, 256, 0, stream>>>(Qr, Kr, Vt, attn_o);

  // out projection: 4096x2048x2048 -> 8x16 = 128 blocks, fp32 out
  gemm256<float><<<128, 512, 0, stream>>>(attn_o, wo_b, out, M, 2048, 2048, 8);
}